// Round 9
// baseline (347.534 us; speedup 1.0000x reference)
//
#include <hip/hip_runtime.h>
#include <hip/hip_bf16.h>

// Problem constants
#define BATCH   4096
#define HIDDEN  128
#define SESS    50
#define KTOT    4096
#define NB      ((size_t)BATCH * HIDDEN)

// GEMM tiling: block = 128 rows x 128 cols x K-eighth (512); BK=32 per tile.
#define MROWS   128
#define KSP     8                    // k-splits (sibling group size)
#define KQL     512                  // k per split
#define BK      32
#define NTL     (KQL / BK)           // 16 tiles
#define ABY     16384                // 128 rows * 32 k * 4B
#define BBY     8192                 // 32 k * 128 cols * 2B
#define BUF     (ABY + BBY)          // 24576
#define NBUF    5                    // 122880 B LDS -> depth-4 prefetch, 1 blk/CU

typedef __bf16 bf16x8 __attribute__((ext_vector_type(8)));
typedef float  f32x4  __attribute__((ext_vector_type(4)));

__device__ __forceinline__ f32x4 mfma_bf16(bf16x8 a, bf16x8 b, f32x4 c) {
    return __builtin_amdgcn_mfma_f32_16x16x32_bf16(a, b, c, 0, 0, 0);
}

// Async global->LDS, 16B/lane. LDS dest = wave-uniform base (+lane*16 by HW);
// global src is per-lane (swizzles live on the source side). Tracked by vmcnt.
__device__ __forceinline__ void gload16(const void* g, void* l) {
    __builtin_amdgcn_global_load_lds(
        (const __attribute__((address_space(1))) void*)g,
        (__attribute__((address_space(3))) void*)l, 16, 0, 0);
}

// Packed B layout (BYTES), XOR-swizzled for conflict-free ds_read_b128:
//   elem(k,h) -> (k>>3)*2048 + [ (h>>4)*256 + (h&15)*16 + (k&7)*2 ] ^ (((k>>3)&3)<<4)
// BK=32 tile = 4 consecutive chunks (8KB, chunk%4 == quad in-tile).
// A-tile LDS: [128 rows][128B]; within-row byte x holds global byte
// x ^ ((row&7)<<4)  (16B-granule involution on stage & read sides).

// ---------------------------------------------------------------------------
// Gather: E[b][h] = sum_s emb[items[b][s]][h] -> packed bf16 ETp (layout above).
// Also zeroes the 64 split-K semaphores (runs before both GEMMs, stream order).
// 1024 blocks x 256 thr, tiny LDS -> 32 waves/CU.
// ---------------------------------------------------------------------------
__global__ __launch_bounds__(256)
void gather_sum_kernel(const float* __restrict__ emb,
                       const int* __restrict__ items32,
                       __bf16* __restrict__ ETp,
                       int* __restrict__ cnt) {
    __shared__ int sidx[4][SESS];
    const int t  = threadIdx.x;
    const int b0 = blockIdx.x * 4;
    if (blockIdx.x == 0 && t < 64) cnt[t] = 0;
    const bool is64 = (items32[1] | items32[3] | items32[5] | items32[7] |
                       items32[9] | items32[11] | items32[13] | items32[15]) == 0;
    if (t < 4 * SESS) {
        const int w_ = t / SESS, s_ = t % SESS;
        sidx[w_][s_] = is64
            ? (int)((const long long*)items32)[(long)(b0 + w_) * SESS + s_]
            : items32[(b0 + w_) * SESS + s_];
    }
    __syncthreads();
    const int w    = t >> 6;
    const int lane = t & 63;
    const int c    = lane & 31;
    const int h    = lane >> 5;
    f32x4 acc = {0.f, 0.f, 0.f, 0.f};
#pragma unroll
    for (int i = 0; i < 25; ++i) {
        acc += *(const f32x4*)(emb + (long)sidx[w][h + 2 * i] * HIDDEN + c * 4);
    }
#pragma unroll
    for (int j = 0; j < 4; ++j) acc[j] += __shfl_xor(acc[j], 32, 64);
    if (h == 0) {
        const int  b     = b0 + w;
        const long chunk = b >> 3;
        const int  swz   = (int)((chunk & 3) << 4);
        char* basep = (char*)ETp + chunk * 2048 + (b & 7) * 2;
        const int hi4 = (c >> 2) * 256;          // (h>>4)*256
#pragma unroll
        for (int j = 0; j < 4; ++j) {
            const int hl = 4 * (c & 3) + j;      // h&15
            *(__bf16*)(basep + ((hi4 + hl * 16) ^ swz)) = (__bf16)acc[j];
        }
    }
}

// ---------------------------------------------------------------------------
// GEMM v10 (R8 body + folded split-K reduction): partial[kq] = X[128r x 512k]
// @ Bp[512k x 128]. grid (32,8) x 256thr = 256 blocks = 1/CU, all co-resident
// (120KB LDS guarantees 1/CU; grid == CU count -> spin-sync is safe).
// After the K-loop: store fp32 partial -> release fence -> bump cnt[mb] ->
// spin until all 8 k-siblings arrive -> each block reduces its OWN 16-row
// slice of the 8 partials (64KB, parallel across all 256 blocks).
// PHASE 1 tail: pack bf16 TTp. PHASE 2 tail: row L2-normalize -> out.
// K-loop: 5-buffer ring, depth-4 prefetch, one barrier/tile, counted
// vmcnt(18/12/6/0). C/D: row = quad*4+reg, col = lane&15 [m89/m91].
// ---------------------------------------------------------------------------
template <int PHASE>
__global__ __launch_bounds__(256, 1)
void gemm_mfma_kernel(const float* __restrict__ X,
                      const char* __restrict__ Bpk,
                      float* __restrict__ Tp,
                      __bf16* __restrict__ TTp,
                      float* __restrict__ out,
                      int* __restrict__ cnt) {
    __shared__ __align__(16) char lds[NBUF * BUF];   // 122880 B
    const int tid  = threadIdx.x;
    const int w    = tid >> 6;
    const int lane = tid & 63;
    const int lo   = lane & 15;
    const int quad = lane >> 4;
    const int mb   = blockIdx.x;
    const int kq   = blockIdx.y;
    const int rowBase = mb * MROWS;

    const int mh = w & 1;
    const int nh = w >> 1;
    const int akey = (lo & 7) << 4;
    const int bkey = quad << 4;

#define STG(t_, dst_) do {                                                   \
    _Pragma("unroll")                                                        \
    for (int ai_ = 0; ai_ < 4; ++ai_) {                                      \
        const int i_  = 4 * w + ai_;                                         \
        const int rl_ = 8 * i_ + (lane >> 3);     /* local row 0..127 */     \
        gload16((const char*)X +                                             \
                    ((size_t)(rowBase + rl_) * KTOT + kq * KQL +             \
                     (size_t)(t_) * BK) * 4 +                                \
                    ((((lane & 7) * 16)) ^ ((rl_ & 7) << 4)),                \
                (dst_) + i_ * 1024);                                         \
    }                                                                        \
    _Pragma("unroll")                                                        \
    for (int bi_ = 0; bi_ < 2; ++bi_) {                                      \
        const int j_ = 2 * w + bi_;                                          \
        gload16(Bpk + ((size_t)(kq * 64 + (t_) * 4 + (j_ >> 1))) * 2048 +    \
                    (j_ & 1) * 1024 + lane * 16,                             \
                (dst_) + ABY + j_ * 1024);                                   \
    }                                                                        \
} while (0)

    f32x4 acc[4][4];
#pragma unroll
    for (int i = 0; i < 4; ++i)
#pragma unroll
        for (int j = 0; j < 4; ++j) acc[i][j] = (f32x4){0.f, 0.f, 0.f, 0.f};

#define KTL(cb_) do {                                                        \
    const char* Ab_ = (cb_);                                                 \
    const char* Bb_ = (cb_) + ABY + quad * 2048;                             \
    bf16x8 af_[4];                                                           \
    _Pragma("unroll")                                                        \
    for (int fm_ = 0; fm_ < 4; ++fm_) {                                      \
        const int rr_ = (mh * 64 + fm_ * 16 + lo) * 128;                     \
        const f32x4 a0_ = *(const f32x4*)(Ab_ + rr_ + ((quad * 32) ^ akey)); \
        const f32x4 a1_ =                                                    \
            *(const f32x4*)(Ab_ + rr_ + ((quad * 32 + 16) ^ akey));          \
        af_[fm_][0] = (__bf16)a0_[0]; af_[fm_][1] = (__bf16)a0_[1];          \
        af_[fm_][2] = (__bf16)a0_[2]; af_[fm_][3] = (__bf16)a0_[3];          \
        af_[fm_][4] = (__bf16)a1_[0]; af_[fm_][5] = (__bf16)a1_[1];          \
        af_[fm_][6] = (__bf16)a1_[2]; af_[fm_][7] = (__bf16)a1_[3];          \
    }                                                                        \
    bf16x8 bf_[4];                                                           \
    _Pragma("unroll")                                                        \
    for (int fn_ = 0; fn_ < 4; ++fn_)                                        \
        bf_[fn_] = *(const bf16x8*)(Bb_ +                                    \
            ((((nh * 4 + fn_) * 256) + lo * 16) ^ bkey));                    \
    _Pragma("unroll")                                                        \
    for (int fm_ = 0; fm_ < 4; ++fm_)                                        \
        _Pragma("unroll")                                                    \
        for (int fn_ = 0; fn_ < 4; ++fn_)                                    \
            acc[fm_][fn_] = mfma_bf16(af_[fm_], bf_[fn_], acc[fm_][fn_]);    \
} while (0)

    // prologue: 4 tiles in flight (24 vmem ops/wave)
    STG(0, lds + 0 * BUF);
    STG(1, lds + 1 * BUF);
    STG(2, lds + 2 * BUF);
    STG(3, lds + 3 * BUF);

#pragma unroll
    for (int t = 0; t < NTL; ++t) {
        if (t <= NTL - 4)
            asm volatile("s_waitcnt vmcnt(18)" ::: "memory");
        else if (t == NTL - 3)
            asm volatile("s_waitcnt vmcnt(12)" ::: "memory");
        else if (t == NTL - 2)
            asm volatile("s_waitcnt vmcnt(6)" ::: "memory");
        else
            asm volatile("s_waitcnt vmcnt(0)" ::: "memory");
        __builtin_amdgcn_s_barrier();     // all waves: tile-t staged, t-1 read
        __builtin_amdgcn_sched_barrier(0);
        if (t + 4 < NTL) STG(t + 4, lds + ((t + 4) % NBUF) * BUF);
        KTL(lds + (t % NBUF) * BUF);
        __builtin_amdgcn_sched_barrier(0);
    }
#undef STG
#undef KTL

    // fp32 partial: row = rowBase + mh*64 + fm*16 + quad*4 + r,
    //               col = nh*64 + fn*16 + lo
    float* op = Tp + (size_t)kq * NB +
                (size_t)(rowBase + mh * 64) * HIDDEN + nh * 64;
#pragma unroll
    for (int fm = 0; fm < 4; ++fm)
#pragma unroll
        for (int r = 0; r < 4; ++r) {
            const int ro = (fm * 16 + quad * 4 + r) * HIDDEN;
#pragma unroll
            for (int fn = 0; fn < 4; ++fn)
                op[ro + fn * 16 + lo] = acc[fm][fn][r];
        }

    // ---- split-K group sync: release stores, bump semaphore, spin to 8.
    __threadfence();                       // flush this thread's stores
    __syncthreads();                       // whole block's stores flushed
    if (tid == 0) {
        atomicAdd(&cnt[mb], 1);
        while (__hip_atomic_load(&cnt[mb], __ATOMIC_ACQUIRE,
                                 __HIP_MEMORY_SCOPE_AGENT) < KSP)
            __builtin_amdgcn_s_sleep(2);
    }
    __syncthreads();
    __threadfence();                       // acquire: invalidate stale lines

    // ---- folded reduction: this block owns rows r0..r0+15 of the slab.
    const int r0 = rowBase + kq * 16;
    if constexpr (PHASE == 1) {
        // sum 8 partials -> packed bf16 TTp (gemm-B layout)
        for (int i = tid; i < 512; i += 256) {       // 512 f32x4 = 16x128
            const size_t off = (size_t)r0 * HIDDEN + (size_t)i * 4;
            f32x4 a = *(const f32x4*)(Tp + off);
#pragma unroll
            for (int p = 1; p < KSP; ++p)
                a += *(const f32x4*)(Tp + (size_t)p * NB + off);
            const int  b     = (int)(off >> 7);
            const int  h0    = (int)(off & 127);
            const long chunk = b >> 3;
            const int  swz   = (int)((chunk & 3) << 4);
            char* basep = (char*)TTp + chunk * 2048 + (b & 7) * 2;
#pragma unroll
            for (int j = 0; j < 4; ++j) {
                const int h = h0 + j;
                *(__bf16*)(basep + (((h >> 4) * 256 + (h & 15) * 16) ^ swz)) =
                    (__bf16)a[j];
            }
        }
    } else {
        // sum 8 partials -> LDS tile -> row L2-normalize -> out
        float (*Cs)[132] = (float (*)[132])lds;      // 16 x 132 x 4B = 8.4 KB
        for (int i = tid; i < 512; i += 256) {
            const size_t off = (size_t)r0 * HIDDEN + (size_t)i * 4;
            f32x4 a = *(const f32x4*)(Tp + off);
#pragma unroll
            for (int p = 1; p < KSP; ++p)
                a += *(const f32x4*)(Tp + (size_t)p * NB + off);
            *(f32x4*)&Cs[(i * 4) >> 7][(i * 4) & 127] = a;
        }
        __syncthreads();
        const int row = tid >> 4;                    // 0..15
        const int cg  = tid & 15;
        const f32x4 c0 = *(const f32x4*)&Cs[row][cg * 8];
        const f32x4 c1 = *(const f32x4*)&Cs[row][cg * 8 + 4];
        float sq = c0[0] * c0[0] + c0[1] * c0[1] + c0[2] * c0[2] +
                   c0[3] * c0[3] + c1[0] * c1[0] + c1[1] * c1[1] +
                   c1[2] * c1[2] + c1[3] * c1[3];
#pragma unroll
        for (int m = 1; m < 16; m <<= 1) sq += __shfl_xor(sq, m, 64);
        const float s = rsqrtf(sq);
        float* opn = out + (size_t)(r0 + row) * HIDDEN + cg * 8;
        f32x4 o0, o1;
#pragma unroll
        for (int j = 0; j < 4; ++j) { o0[j] = c0[j] * s; o1[j] = c1[j] * s; }
        *(f32x4*)(opn)     = o0;
        *(f32x4*)(opn + 4) = o1;
    }
}

// ---------------------------------------------------------------------------
// out = normalize_rows( D @ (A @ E) )
// 3 dispatches: gather(+zero semaphores) -> gemm<1> (split-K + folded pack)
// -> gemm<2> (split-K + folded normalize).
// ws: cnt 1KB | ETp 1MB | TTp 1MB | Tp fp32 x8 16MB  (~18 MB)
// ---------------------------------------------------------------------------
extern "C" void kernel_launch(void* const* d_in, const int* in_sizes, int n_in,
                              void* d_out, int out_size, void* d_ws, size_t ws_size,
                              hipStream_t stream) {
    const float* emb   = (const float*)d_in[0];
    const int*   items = (const int*)d_in[1];
    const float* A     = (const float*)d_in[2];
    const float* D     = (const float*)d_in[3];
    float* out = (float*)d_out;

    int*    cnt = (int*)d_ws;                      // 64 ints (2 x 32)
    __bf16* ETp = (__bf16*)((char*)d_ws + 1024);
    __bf16* TTp = ETp + NB;
    float*  Tp  = (float*)(TTp + NB);

    gather_sum_kernel<<<BATCH / 4, 256, 0, stream>>>(emb, items, ETp, cnt);
    gemm_mfma_kernel<1><<<dim3(32, KSP), 256, 0, stream>>>(
        A, (const char*)ETp, Tp, TTp, nullptr, cnt);
    gemm_mfma_kernel<2><<<dim3(32, KSP), 256, 0, stream>>>(
        D, (const char*)TTp, Tp, nullptr, out, cnt + 32);
}

// Round 10
// 217.101 us; speedup vs baseline: 1.6008x; 1.6008x over previous
//
#include <hip/hip_runtime.h>
#include <hip/hip_bf16.h>

// Problem constants
#define BATCH   4096
#define HIDDEN  128
#define SESS    50
#define KTOT    4096
#define NB      ((size_t)BATCH * HIDDEN)

// GEMM tiling: block = 128 rows x 128 cols x K-eighth (512); BK=32 per tile.
#define MROWS   128
#define KSP     8                    // k-splits
#define KQL     512                  // k per split
#define BK      32
#define NTL     (KQL / BK)           // 16 tiles
#define ABY     16384                // 128 rows * 32 k * 4B
#define BBY     8192                 // 32 k * 128 cols * 2B
#define BUF     (ABY + BBY)          // 24576
#define NBUF    5                    // 122880 B LDS -> depth-4 prefetch, 1 blk/CU

typedef __bf16 bf16x8 __attribute__((ext_vector_type(8)));
typedef float  f32x4  __attribute__((ext_vector_type(4)));
typedef float  f32x2  __attribute__((ext_vector_type(2)));

__device__ __forceinline__ f32x4 mfma_bf16(bf16x8 a, bf16x8 b, f32x4 c) {
    return __builtin_amdgcn_mfma_f32_16x16x32_bf16(a, b, c, 0, 0, 0);
}

// Async global->LDS, 16B/lane. LDS dest = wave-uniform base (+lane*16 by HW);
// global src is per-lane (swizzles live on the source side). Tracked by vmcnt.
__device__ __forceinline__ void gload16(const void* g, void* l) {
    __builtin_amdgcn_global_load_lds(
        (const __attribute__((address_space(1))) void*)g,
        (__attribute__((address_space(3))) void*)l, 16, 0, 0);
}

// Packed B layout (BYTES), XOR-swizzled for conflict-free ds_read_b128:
//   elem(k,h) -> (k>>3)*2048 + [ (h>>4)*256 + (h&15)*16 + (k&7)*2 ] ^ (((k>>3)&3)<<4)
// BK=32 tile = 4 consecutive chunks (8KB, chunk%4 == quad in-tile).
// A-tile LDS: [128 rows][128B]; within-row byte x holds global byte
// x ^ ((row&7)<<4)  (16B-granule involution on stage & read sides).

// ---------------------------------------------------------------------------
// Gather: E[b][h] = sum_s emb[items[b][s]][h] -> packed bf16 ETp (layout above).
// 1024 blocks x 256 thr, tiny LDS -> 32 waves/CU (R3-proven).
// ---------------------------------------------------------------------------
__global__ __launch_bounds__(256)
void gather_sum_kernel(const float* __restrict__ emb,
                       const int* __restrict__ items32,
                       __bf16* __restrict__ ETp) {
    __shared__ int sidx[4][SESS];
    const int t  = threadIdx.x;
    const int b0 = blockIdx.x * 4;
    const bool is64 = (items32[1] | items32[3] | items32[5] | items32[7] |
                       items32[9] | items32[11] | items32[13] | items32[15]) == 0;
    if (t < 4 * SESS) {
        const int w_ = t / SESS, s_ = t % SESS;
        sidx[w_][s_] = is64
            ? (int)((const long long*)items32)[(long)(b0 + w_) * SESS + s_]
            : items32[(b0 + w_) * SESS + s_];
    }
    __syncthreads();
    const int w    = t >> 6;
    const int lane = t & 63;
    const int c    = lane & 31;
    const int h    = lane >> 5;
    f32x4 acc = {0.f, 0.f, 0.f, 0.f};
#pragma unroll
    for (int i = 0; i < 25; ++i) {
        acc += *(const f32x4*)(emb + (long)sidx[w][h + 2 * i] * HIDDEN + c * 4);
    }
#pragma unroll
    for (int j = 0; j < 4; ++j) acc[j] += __shfl_xor(acc[j], 32, 64);
    if (h == 0) {
        const int  b     = b0 + w;
        const long chunk = b >> 3;
        const int  swz   = (int)((chunk & 3) << 4);
        char* basep = (char*)ETp + chunk * 2048 + (b & 7) * 2;
        const int hi4 = (c >> 2) * 256;          // (h>>4)*256
#pragma unroll
        for (int j = 0; j < 4; ++j) {
            const int hl = 4 * (c & 3) + j;      // h&15
            *(__bf16*)(basep + ((hi4 + hl * 16) ^ swz)) = (__bf16)acc[j];
        }
    }
}

// ---------------------------------------------------------------------------
// GEMM v11 (R8 geometry, 8 waves): partial[kq] = X[128r x 512k] @ Bp[512k x 128].
// grid (32,8) x 512thr = 256 blocks, 1/CU, 8 waves/CU issuing staging ops
// (the R8->R10 A/B: bytes/depth/barriers held constant, issuing waves 2x).
// 5-buffer LDS ring, depth-4 prefetch, one barrier/tile, counted
// vmcnt(9/6/3/0) (3 gloads/wave/tile: 2 A + 1 B). Wave w: rows 32*(w&3)..+31,
// cols 64*(w>>2)..+63 -> acc[2][4], 8 MFMAs/tile.
// C/D layout: row = quad*4 + reg, col = lane&15 [HW-verified m89/m91].
// fp32 partial out at Tp + kq*NB.
// ---------------------------------------------------------------------------
__global__ __launch_bounds__(512, 1)
void gemm_mfma_kernel(const float* __restrict__ X,
                      const char* __restrict__ Bpk,
                      float* __restrict__ Tp) {
    __shared__ __align__(16) char lds[NBUF * BUF];   // 122880 B
    const int tid  = threadIdx.x;
    const int w    = tid >> 6;
    const int lane = tid & 63;
    const int lo   = lane & 15;
    const int quad = lane >> 4;
    const int rowBase = blockIdx.x * MROWS;
    const int kq      = blockIdx.y;

    const int mq = w & 3;            // 32-row quarter
    const int nh = w >> 2;           // 64-col half
    const int akey = (lo & 7) << 4;
    const int bkey = quad << 4;

    // staging per tile: 16 A ops (1KB = 8 rows each) + 8 B ops (1KB each);
    // wave w -> A ops {2w,2w+1}, B op {w}.  (3 ops/wave/tile)
#define STG(t_, dst_) do {                                                   \
    _Pragma("unroll")                                                        \
    for (int ai_ = 0; ai_ < 2; ++ai_) {                                      \
        const int i_  = 2 * w + ai_;                                         \
        const int rl_ = 8 * i_ + (lane >> 3);     /* local row 0..127 */     \
        gload16((const char*)X +                                             \
                    ((size_t)(rowBase + rl_) * KTOT + kq * KQL +             \
                     (size_t)(t_) * BK) * 4 +                                \
                    ((((lane & 7) * 16)) ^ ((rl_ & 7) << 4)),                \
                (dst_) + i_ * 1024);                                         \
    }                                                                        \
    {                                                                        \
        const int j_ = w;                                                    \
        gload16(Bpk + ((size_t)(kq * 64 + (t_) * 4 + (j_ >> 1))) * 2048 +    \
                    (j_ & 1) * 1024 + lane * 16,                             \
                (dst_) + ABY + j_ * 1024);                                   \
    }                                                                        \
} while (0)

    f32x4 acc[2][4];
#pragma unroll
    for (int i = 0; i < 2; ++i)
#pragma unroll
        for (int j = 0; j < 4; ++j) acc[i][j] = (f32x4){0.f, 0.f, 0.f, 0.f};

#define KTL(cb_) do {                                                        \
    const char* Ab_ = (cb_);                                                 \
    const char* Bb_ = (cb_) + ABY + quad * 2048;                             \
    bf16x8 af_[2];                                                           \
    _Pragma("unroll")                                                        \
    for (int fm_ = 0; fm_ < 2; ++fm_) {                                      \
        const int rr_ = (mq * 32 + fm_ * 16 + lo) * 128;                     \
        const f32x4 a0_ = *(const f32x4*)(Ab_ + rr_ + ((quad * 32) ^ akey)); \
        const f32x4 a1_ =                                                    \
            *(const f32x4*)(Ab_ + rr_ + ((quad * 32 + 16) ^ akey));          \
        af_[fm_][0] = (__bf16)a0_[0]; af_[fm_][1] = (__bf16)a0_[1];          \
        af_[fm_][2] = (__bf16)a0_[2]; af_[fm_][3] = (__bf16)a0_[3];          \
        af_[fm_][4] = (__bf16)a1_[0]; af_[fm_][5] = (__bf16)a1_[1];          \
        af_[fm_][6] = (__bf16)a1_[2]; af_[fm_][7] = (__bf16)a1_[3];          \
    }                                                                        \
    bf16x8 bf_[4];                                                           \
    _Pragma("unroll")                                                        \
    for (int fn_ = 0; fn_ < 4; ++fn_)                                        \
        bf_[fn_] = *(const bf16x8*)(Bb_ +                                    \
            ((((nh * 4 + fn_) * 256) + lo * 16) ^ bkey));                    \
    _Pragma("unroll")                                                        \
    for (int fm_ = 0; fm_ < 2; ++fm_)                                        \
        _Pragma("unroll")                                                    \
        for (int fn_ = 0; fn_ < 4; ++fn_)                                    \
            acc[fm_][fn_] = mfma_bf16(af_[fm_], bf_[fn_], acc[fm_][fn_]);    \
} while (0)

    // prologue: 4 tiles in flight (12 vmem ops/wave)
    STG(0, lds + 0 * BUF);
    STG(1, lds + 1 * BUF);
    STG(2, lds + 2 * BUF);
    STG(3, lds + 3 * BUF);

#pragma unroll
    for (int t = 0; t < NTL; ++t) {
        // wait own tile-t ops (oldest 3): min(9, (NTL-1-t)*3)
        if (t <= NTL - 4)
            asm volatile("s_waitcnt vmcnt(9)" ::: "memory");
        else if (t == NTL - 3)
            asm volatile("s_waitcnt vmcnt(6)" ::: "memory");
        else if (t == NTL - 2)
            asm volatile("s_waitcnt vmcnt(3)" ::: "memory");
        else
            asm volatile("s_waitcnt vmcnt(0)" ::: "memory");
        __builtin_amdgcn_s_barrier();     // all waves: tile-t staged, t-1 read
        __builtin_amdgcn_sched_barrier(0);
        if (t + 4 < NTL) STG(t + 4, lds + ((t + 4) % NBUF) * BUF);
        KTL(lds + (t % NBUF) * BUF);
        __builtin_amdgcn_sched_barrier(0);
    }
#undef STG
#undef KTL

    // fp32 partial: row = rowBase + mq*32 + fm*16 + quad*4 + r,
    //               col = nh*64 + fn*16 + lo  (16-lane coalesced rows)
    float* op = Tp + (size_t)kq * NB +
                (size_t)(rowBase + mq * 32) * HIDDEN + nh * 64;
#pragma unroll
    for (int fm = 0; fm < 2; ++fm)
#pragma unroll
        for (int r = 0; r < 4; ++r) {
            const int ro = (fm * 16 + quad * 4 + r) * HIDDEN;
#pragma unroll
            for (int fn = 0; fn < 4; ++fn)
                op[ro + fn * 16 + lo] = acc[fm][fn][r];
        }
}

// ---------------------------------------------------------------------------
// reduce8_pack: TTp(packed bf16) = sum of 8 k-split partials.
// ---------------------------------------------------------------------------
__global__ __launch_bounds__(256)
void reduce8_kernel(const float* __restrict__ Tp, __bf16* __restrict__ TTp) {
    const size_t i = ((size_t)blockIdx.x * 256 + threadIdx.x) * 4;
    f32x4 a = *(const f32x4*)(Tp + i);
#pragma unroll
    for (int p = 1; p < KSP; ++p) a += *(const f32x4*)(Tp + p * NB + i);
    const int  b     = (int)(i >> 7);
    const int  h0    = (int)(i & 127);
    const long chunk = b >> 3;
    const int  swz   = (int)((chunk & 3) << 4);
    char* basep = (char*)TTp + chunk * 2048 + (b & 7) * 2;
#pragma unroll
    for (int j = 0; j < 4; ++j) {
        const int h = h0 + j;
        *(__bf16*)(basep + (((h >> 4) * 256 + (h & 15) * 16) ^ swz)) =
            (__bf16)a[j];
    }
}

// ---------------------------------------------------------------------------
// rednorm8: out[row] = normalize(sum of 8 partials). One wave per row.
// ---------------------------------------------------------------------------
__global__ __launch_bounds__(256)
void rednorm8_kernel(const float* __restrict__ Tp, float* __restrict__ out) {
    const int t    = threadIdx.x;
    const int w    = t >> 6;
    const int lane = t & 63;
    const int row  = blockIdx.x * 4 + w;
    const size_t base = (size_t)row * HIDDEN + lane * 2;
    f32x2 v = *(const f32x2*)(Tp + base);
#pragma unroll
    for (int p = 1; p < KSP; ++p) v += *(const f32x2*)(Tp + p * NB + base);
    float sq = v[0] * v[0] + v[1] * v[1];
#pragma unroll
    for (int m = 1; m < 64; m <<= 1) sq += __shfl_xor(sq, m, 64);
    const float s = rsqrtf(sq);
    f32x2 o = {v[0] * s, v[1] * s};
    *(f32x2*)(out + base) = o;
}

// ---------------------------------------------------------------------------
// out = normalize_rows( D @ (A @ E) )
// 5 dispatches: gather -> gemm(A,E) 8 partials -> reduce8 (pack TTp) ->
// gemm(D,T) 8 partials -> rednorm8.
// ws: ETp 1MB | TTp 1MB | Tp fp32 x8 16MB  (~18 MB)
// ---------------------------------------------------------------------------
extern "C" void kernel_launch(void* const* d_in, const int* in_sizes, int n_in,
                              void* d_out, int out_size, void* d_ws, size_t ws_size,
                              hipStream_t stream) {
    const float* emb   = (const float*)d_in[0];
    const int*   items = (const int*)d_in[1];
    const float* A     = (const float*)d_in[2];
    const float* D     = (const float*)d_in[3];
    float* out = (float*)d_out;

    __bf16* ETp = (__bf16*)d_ws;
    __bf16* TTp = ETp + NB;
    float*  Tp  = (float*)(TTp + NB);

    gather_sum_kernel<<<BATCH / 4, 256, 0, stream>>>(emb, items, ETp);
    gemm_mfma_kernel<<<dim3(BATCH / MROWS, KSP), 512, 0, stream>>>(
        A, (const char*)ETp, Tp);
    reduce8_kernel<<<512, 256, 0, stream>>>(Tp, TTp);
    gemm_mfma_kernel<<<dim3(BATCH / MROWS, KSP), 512, 0, stream>>>(
        D, (const char*)TTp, Tp);
    rednorm8_kernel<<<BATCH / 4, 256, 0, stream>>>(Tp, out);
}

// Round 11
// 208.446 us; speedup vs baseline: 1.6673x; 1.0415x over previous
//
#include <hip/hip_runtime.h>
#include <hip/hip_bf16.h>

// Problem constants
#define BATCH   4096
#define HIDDEN  128
#define SESS    50
#define KTOT    4096
#define NB      ((size_t)BATCH * HIDDEN)

// GEMM tiling: block = 16 rows x 128 cols x full K; BK=128 per LDS tile.
#define BK      128
#define NTILES  (KTOT / BK)          // 32
#define ABYTES  8192                 // 16 rows * 128 k * 4B
#define BBYTES  32768                // 128 k * 128 cols * 2B
#define BUF     (ABYTES + BBYTES)    // 40960; x3 buffers = 122880 B LDS

typedef __bf16 bf16x8 __attribute__((ext_vector_type(8)));
typedef __bf16 bf16x4 __attribute__((ext_vector_type(4)));
typedef float  f32x4  __attribute__((ext_vector_type(4)));

__device__ __forceinline__ f32x4 mfma_bf16(bf16x8 a, bf16x8 b, f32x4 c) {
    return __builtin_amdgcn_mfma_f32_16x16x32_bf16(a, b, c, 0, 0, 0);
}

// Async global->LDS, 16B/lane. LDS dest = wave-uniform base (+lane*16 by HW);
// global src is per-lane (swizzles live on the source side). Tracked by vmcnt.
__device__ __forceinline__ void gload16(const void* g, void* l) {
    __builtin_amdgcn_global_load_lds(
        (const __attribute__((address_space(1))) void*)g,
        (__attribute__((address_space(3))) void*)l, 16, 0, 0);
}

// Packed B layout (BYTES), XOR-swizzled for conflict-free ds_read_b128:
//   elem(k,h) -> (k>>3)*2048 + [ (h>>4)*256 + (h&15)*16 + (k&7)*2 ] ^ (((k>>3)&3)<<4)
// K-loop read (tile-local chunk c = ks*4+quad, so c&3 == quad):
//   byte = c*2048 + ((nt*256 + lo*16) ^ (quad<<4))  -> granule (lo^quad)&7: even spread.
// A-tile LDS layout: [row][512B] linear rows; within-row byte w holds global
// byte (w ^ ((row&7)<<4)) -> ds_read granule ((base>>4) ^ (lo&7)): even spread.

// ---------------------------------------------------------------------------
// Gather: E[b][h] = sum_s emb[items[b][s]][h] -> packed bf16 ETp (layout above).
// ---------------------------------------------------------------------------
__global__ __launch_bounds__(256)
void gather_sum_kernel(const float* __restrict__ emb,
                       const int* __restrict__ items32,
                       __bf16* __restrict__ ETp) {
    __shared__ int sidx[4][SESS];
    const int t  = threadIdx.x;
    const int b0 = blockIdx.x * 4;
    const bool is64 = (items32[1] | items32[3] | items32[5] | items32[7] |
                       items32[9] | items32[11] | items32[13] | items32[15]) == 0;
    if (t < 4 * SESS) {
        const int w_ = t / SESS, s_ = t % SESS;
        sidx[w_][s_] = is64
            ? (int)((const long long*)items32)[(long)(b0 + w_) * SESS + s_]
            : items32[(b0 + w_) * SESS + s_];
    }
    __syncthreads();
    const int w    = t >> 6;
    const int lane = t & 63;
    const int c    = lane & 31;
    const int h    = lane >> 5;
    f32x4 acc = {0.f, 0.f, 0.f, 0.f};
#pragma unroll
    for (int i = 0; i < 25; ++i) {
        acc += *(const f32x4*)(emb + (long)sidx[w][h + 2 * i] * HIDDEN + c * 4);
    }
#pragma unroll
    for (int j = 0; j < 4; ++j) acc[j] += __shfl_xor(acc[j], 32, 64);
    if (h == 0) {
        const int  b     = b0 + w;
        const long chunk = b >> 3;
        const int  swz   = (int)((chunk & 3) << 4);
        char* basep = (char*)ETp + chunk * 2048 + (b & 7) * 2;
        const int hi4 = (c >> 2) * 256;          // (h>>4)*256
#pragma unroll
        for (int j = 0; j < 4; ++j) {
            const int hl = 4 * (c & 3) + j;      // h&15
            *(__bf16*)(basep + ((hi4 + hl * 16) ^ swz)) = (__bf16)acc[j];
        }
    }
}

// ---------------------------------------------------------------------------
// GEMM (pure-LDS K-loop; empirical optimum over 11 structural variants):
// C[16x128] = X[16x4096] @ Bpk[4096x128].
// grid 256 x 256thr (4 waves). Per BK=128 tile both operands staged to LDS by
// global_load_lds (10 ops/wave: 2 A + 8 B), triple-buffered, prefetch depth 2,
// counted vmcnt(20/10/0), raw s_barrier (no drain in loop). K-loop is
// ds_read + cvt + MFMA only -- zero global loads, compiler-managed lgkmcnt.
// Wave w owns n-tiles {2w,2w+1} full-K: private accs, no cross-wave reduce.
// C/D layout: row = quad*4 + reg, col = lane&15 [HW-verified m89/m91].
// PHASE 1: direct packed-bf16 store of T. PHASE 2: fused row L2-normalize.
// ---------------------------------------------------------------------------
template <int PHASE>
__global__ __launch_bounds__(256, 1)
void gemm_mfma_kernel(const float* __restrict__ X,
                      const __bf16* __restrict__ Bpk,
                      __bf16* __restrict__ TTp,
                      float* __restrict__ out) {
    __shared__ __align__(16) char lds[3 * BUF];   // 122880 B
    const int tid  = threadIdx.x;
    const int w    = tid >> 6;
    const int lane = tid & 63;
    const int lo   = lane & 15;
    const int quad = lane >> 4;
    const int rowBase = blockIdx.x * 16;

    // ---- staging: wave w -> A ops {2w,2w+1} (2 rows each), B ops {8w..8w+7}
#define STAGE(t_, dst_) do {                                                 \
    _Pragma("unroll")                                                        \
    for (int oi_ = 0; oi_ < 2; ++oi_) {                                      \
        const int o_    = 2 * w + oi_;                                       \
        const int rloc_ = 2 * o_ + (lane >> 5);                              \
        gload16((const char*)X +                                             \
                    ((size_t)(rowBase + rloc_) * KTOT + (size_t)(t_) * BK) * 4 + \
                    (((lane & 31) * 16) ^ ((rloc_ & 7) << 4)),               \
                (dst_) + o_ * 1024);                                         \
    }                                                                        \
    _Pragma("unroll")                                                        \
    for (int bi_ = 0; bi_ < 8; ++bi_) {                                      \
        const int i_ = 8 * w + bi_;                                          \
        gload16((const char*)Bpk + (size_t)(t_) * BBYTES + i_ * 1024 +       \
                    lane * 16,                                               \
                (dst_) + ABYTES + i_ * 1024);                                \
    }                                                                        \
} while (0)

    f32x4 acc0 = {0.f, 0.f, 0.f, 0.f};
    f32x4 acc1 = {0.f, 0.f, 0.f, 0.f};

    const int akey = (lo & 7) << 4;
    const int bswz = quad << 4;
    const int bc0  = (int)(((2 * w) * 256 + lo * 16) ^ bswz);
    const int bc1  = (int)(((2 * w + 1) * 256 + lo * 16) ^ bswz);

#define KTILE(cb_) do {                                                      \
    const char* Ar_ = (cb_) + lo * 512;                                      \
    const char* Bb_ = (cb_) + ABYTES + quad * 2048;                          \
    _Pragma("unroll")                                                        \
    for (int ks_ = 0; ks_ < 4; ++ks_) {                                      \
        const f32x4 a0_ =                                                    \
            *(const f32x4*)(Ar_ + ((ks_ * 128 + quad * 32) ^ akey));         \
        const f32x4 a1_ =                                                    \
            *(const f32x4*)(Ar_ + ((ks_ * 128 + quad * 32 + 16) ^ akey));    \
        const bf16x8 b0_ = *(const bf16x8*)(Bb_ + ks_ * 8192 + bc0);         \
        const bf16x8 b1_ = *(const bf16x8*)(Bb_ + ks_ * 8192 + bc1);         \
        bf16x8 af_;                                                          \
        af_[0] = (__bf16)a0_[0]; af_[1] = (__bf16)a0_[1];                    \
        af_[2] = (__bf16)a0_[2]; af_[3] = (__bf16)a0_[3];                    \
        af_[4] = (__bf16)a1_[0]; af_[5] = (__bf16)a1_[1];                    \
        af_[6] = (__bf16)a1_[2]; af_[7] = (__bf16)a1_[3];                    \
        acc0 = mfma_bf16(af_, b0_, acc0);                                    \
        acc1 = mfma_bf16(af_, b1_, acc1);                                    \
    }                                                                        \
} while (0)

    // prologue: tiles 0,1 in flight (20 vmem ops/wave)
    STAGE(0, lds);
    STAGE(1, lds + BUF);

    char* cb = lds;               // compute buffer (tile t   -> t%3)
    char* sb = lds + 2 * BUF;     // stage buffer   (tile t+2 -> (t+2)%3)
    for (int t = 0; t < NTILES; ++t) {
        if (t + 2 < NTILES) STAGE(t + 2, sb);
        if (t < NTILES - 2)
            asm volatile("s_waitcnt vmcnt(20)" ::: "memory");
        else if (t == NTILES - 2)
            asm volatile("s_waitcnt vmcnt(10)" ::: "memory");
        else
            asm volatile("s_waitcnt vmcnt(0)" ::: "memory");
        __builtin_amdgcn_s_barrier();        // all waves' tile-t staging done
        __builtin_amdgcn_sched_barrier(0);
        KTILE(cb);
        __builtin_amdgcn_s_barrier();        // reads done before t+3 restages
        __builtin_amdgcn_sched_barrier(0);
        cb += BUF; if (cb == lds + 3 * BUF) cb = lds;
        sb += BUF; if (sb == lds + 3 * BUF) sb = lds;
    }
#undef KTILE
#undef STAGE

    if (PHASE == 1) {
        // Direct packed-bf16 store of T (4 acc regs = 4 consecutive packed
        // elems: chunk = rowBase/8 + quad/2, k&7 = (quad&1)*4 + r).
        const long chunk = (rowBase >> 3) + (quad >> 1);
        const int  swz   = (int)((chunk & 3) << 4);
        char* tb = (char*)TTp + chunk * 2048 + (quad & 1) * 8;
        bf16x4 p0, p1;
#pragma unroll
        for (int r = 0; r < 4; ++r) {
            p0[r] = (__bf16)acc0[r];
            p1[r] = (__bf16)acc1[r];
        }
        *(bf16x4*)(tb + (((2 * w) * 256 + lo * 16) ^ swz))     = p0;
        *(bf16x4*)(tb + (((2 * w + 1) * 256 + lo * 16) ^ swz)) = p1;
    } else {
        // Fused row L2-normalize via LDS overlay (all staging drained).
        __syncthreads();
        float (*Cs)[136] = (float (*)[136])lds;
#pragma unroll
        for (int r = 0; r < 4; ++r) {
            Cs[quad * 4 + r][(2 * w) * 16 + lo]     = acc0[r];
            Cs[quad * 4 + r][(2 * w + 1) * 16 + lo] = acc1[r];
        }
        __syncthreads();
        const int row = tid >> 4;
        const int cg  = tid & 15;
        const f32x4 c0 = *(const f32x4*)&Cs[row][cg * 8];
        const f32x4 c1 = *(const f32x4*)&Cs[row][cg * 8 + 4];
        float sq = c0[0] * c0[0] + c0[1] * c0[1] + c0[2] * c0[2] +
                   c0[3] * c0[3] + c1[0] * c1[0] + c1[1] * c1[1] +
                   c1[2] * c1[2] + c1[3] * c1[3];
#pragma unroll
        for (int m = 1; m < 16; m <<= 1) sq += __shfl_xor(sq, m, 64);
        const float s = rsqrtf(sq);
        float* op = out + (size_t)(rowBase + row) * HIDDEN + cg * 8;
        f32x4 o0, o1;
#pragma unroll
        for (int j = 0; j < 4; ++j) { o0[j] = c0[j] * s; o1[j] = c1[j] * s; }
        *(f32x4*)(op)     = o0;
        *(f32x4*)(op + 4) = o1;
    }
}

// ---------------------------------------------------------------------------
// out = normalize_rows( D @ (A @ E) )
// 3 dispatches: gather -> gemm<1> (packed T) -> gemm<2> (fused normalize).
// ws: ETp 1MB | TTp 1MB. Empirical optimum (207.4 us, R3); remaining budget
// is harness fixed cost (~115-135 us/iter) + gather (~30) + 2 GEMMs at their
// latency floor (~31 each) -- all structural attacks on which regressed.
// ---------------------------------------------------------------------------
extern "C" void kernel_launch(void* const* d_in, const int* in_sizes, int n_in,
                              void* d_out, int out_size, void* d_ws, size_t ws_size,
                              hipStream_t stream) {
    const float* emb   = (const float*)d_in[0];
    const int*   items = (const int*)d_in[1];
    const float* A     = (const float*)d_in[2];
    const float* D     = (const float*)d_in[3];
    float* out = (float*)d_out;

    __bf16* ETp = (__bf16*)d_ws;
    __bf16* TTp = ETp + NB;

    gather_sum_kernel<<<BATCH / 4, 256, 0, stream>>>(emb, items, ETp);
    gemm_mfma_kernel<1><<<BATCH / 16, 256, 0, stream>>>(A, ETp, TTp, nullptr);
    gemm_mfma_kernel<2><<<BATCH / 16, 256, 0, stream>>>(D, TTp, nullptr, out);
}